// Round 12
// baseline (178.618 us; speedup 1.0000x reference)
//
#include <hip/hip_runtime.h>
#include <hip/hip_bf16.h>
#include <float.h>

#define B_    16
#define N1_   4096
#define N2_   1024
#define C2_   256
#define OUT_  256
#define K_    4096    // GEMM K == N1
#define SPLITK 8
#define KCH_  (K_ / SPLITK)     // 512

typedef short short8 __attribute__((ext_vector_type(8)));
typedef float float4v __attribute__((ext_vector_type(4)));

static __device__ __forceinline__ unsigned short f32_to_bf16_bits(float v) {
    __hip_bfloat16 h = __float2bfloat16(v);
    return *(unsigned short*)&h;
}

// ---------------------------------------------------------------------------
// Kernel 0 (prep, fused): blocks [0,1024) convert W1 f32->bf16; blocks
// [1024,2048) init Z[b][o][c] = b1[o] (gemm accumulates into Z atomically,
// and d_ws is re-poisoned 0xAA before every call); block 0 zeroes accum.
// ---------------------------------------------------------------------------
__global__ __launch_bounds__(256) void prep_kernel(
    const float* __restrict__ W1, unsigned short* __restrict__ W1b,
    const float* __restrict__ b1, float* __restrict__ Z,
    float* __restrict__ accum)
{
    const int blk = blockIdx.x;
    const int tid = threadIdx.x;
    if (blk == 0) {
        accum[tid] = 0.0f;
        accum[256 + tid] = 0.0f;
    }
    if (blk < 1024) {
        const int i = (blk * 256 + tid) * 4;
        float4 v = *(const float4*)(W1 + i);
        ushort4 o;
        o.x = f32_to_bf16_bits(v.x);
        o.y = f32_to_bf16_bits(v.y);
        o.z = f32_to_bf16_bits(v.z);
        o.w = f32_to_bf16_bits(v.w);
        *(ushort4*)(W1b + i) = o;
    } else {
        const int i = ((blk - 1024) * 256 + tid) * 4;   // Z flat index
        const int o = (i >> 8) & 255;
        const float bv = b1[o];
        *(float4*)(Z + i) = make_float4(bv, bv, bv, bv);
    }
}

// ---------------------------------------------------------------------------
// Fused knn + interp — proven R9 structure (1 query/thread, 64 q/block,
// 1024 blocks = 4 blocks/CU). Key = distance dk = max(ss+2*(0.5|p|^2-dot),0)
// (non-negative -> float order == bit order), candidate index in low 10
// mantissa bits; smaller index wins ties (JAX stable top-k). Truncation
// 2^-13 relative to d -> flips only between near-equal neighbors (benign;
// absmax 0.035). Top-3 via 4-op min/med3/min(max) network; subtract folded
// into fma. Winners' distances recomputed exactly. Phase B: gather + blend +
// LDS-transpose, write bf16 interp_t[b][c][n] (K-major).
// ---------------------------------------------------------------------------
#define TPAD 65
struct KnnSh {
    float4 pts[N2_];          // (x, y, z, 0.5*|p|^2)   16 KB
    float  pf[4][64][3];      // per-wave packed top-3   3 KB
};
union ShUnion {
    KnnSh a;
    unsigned short tile[C2_][TPAD];   // transpose tile  33.3 KB
};

__global__ __launch_bounds__(256) void knn_interp_kernel(
    const float* __restrict__ xyz1,
    const float* __restrict__ xyz2,
    const float* __restrict__ x2,
    unsigned short* __restrict__ interp_t)
{
    __shared__ ShUnion sh;
    __shared__ float rw[64][3];
    __shared__ int   ri[64][3];

    const int b  = blockIdx.y;
    const int n0 = blockIdx.x * 64;
    const int t  = threadIdx.x;
    const int w  = t >> 6;
    const int l  = t & 63;

    // ---- stage candidates into LDS ----
    for (int r = 0; r < 4; ++r) {
        int j = r * 256 + t;
        const float* p = xyz2 + ((size_t)b * N2_ + j) * 3;
        float x = p[0], y = p[1], z = p[2];
        sh.a.pts[j] = make_float4(x, y, z, 0.5f * ((x * x + y * y) + z * z));
    }
    __syncthreads();

    const int n1 = n0 + l;
    const float* q = xyz1 + ((size_t)b * N1_ + n1) * 3;
    const float s0 = q[0], s1 = q[1], s2 = q[2];
    const float ns0 = -s0, ns1 = -s1, ns2 = -s2;
    const float ss = (s0 * s0 + s1 * s1) + s2 * s2;

    // ---- Phase A: scan (wave w covers blocked quarter [256w, 256w+256)) ----
    const int jbase = w << 8;
    float f0 = FLT_MAX, f1 = FLT_MAX, f2 = FLT_MAX;

    #pragma unroll 4
    for (int jj = 0; jj < 256; ++jj) {
        const int j = jbase + jj;
        float4 pq = sh.a.pts[j];
        float acc = fmaf(ns0, pq.x, pq.w);
        acc = fmaf(ns1, pq.y, acc);
        acc = fmaf(ns2, pq.z, acc);
        float dk = fmaxf(fmaf(2.0f, acc, ss), 0.0f);
        float fp = __int_as_float((__float_as_int(dk) & 0xFFFFFC00) | j);
        float nf0 = fminf(fp, f0);
        float nf1 = __builtin_amdgcn_fmed3f(fp, f0, f1);
        float nf2 = fminf(f2, fmaxf(fp, f1));
        f0 = nf0; f1 = nf1; f2 = nf2;
    }

    sh.a.pf[w][l][0] = f0; sh.a.pf[w][l][1] = f1; sh.a.pf[w][l][2] = f2;
    __syncthreads();

    if (w == 0) {
        float g0 = FLT_MAX, g1 = FLT_MAX, g2 = FLT_MAX;
        #pragma unroll
        for (int p = 0; p < 4; ++p)
        #pragma unroll
        for (int r = 0; r < 3; ++r) {
            float fp = sh.a.pf[p][l][r];
            float n0v = fminf(fp, g0);
            float n1v = __builtin_amdgcn_fmed3f(fp, g0, g1);
            float n2v = fminf(g2, fmaxf(fp, g1));
            g0 = n0v; g1 = n1v; g2 = n2v;
        }
        int j0 = __float_as_int(g0) & 1023;
        int j1 = __float_as_int(g1) & 1023;
        int j2 = __float_as_int(g2) & 1023;
        const float4 p0 = sh.a.pts[j0];
        const float4 p1 = sh.a.pts[j1];
        const float4 p2 = sh.a.pts[j2];
        float d0 = ss + 2.0f * (p0.w - ((s0 * p0.x + s1 * p0.y) + s2 * p0.z));
        float d1 = ss + 2.0f * (p1.w - ((s0 * p1.x + s1 * p1.y) + s2 * p1.z));
        float d2 = ss + 2.0f * (p2.w - ((s0 * p2.x + s1 * p2.y) + s2 * p2.z));
        float r0 = 1.0f / (d0 + 1e-8f);
        float r1 = 1.0f / (d1 + 1e-8f);
        float r2 = 1.0f / (d2 + 1e-8f);
        float s  = (r0 + r1) + r2;
        rw[l][0] = r0 / s;  rw[l][1] = r1 / s;  rw[l][2] = r2 / s;
        ri[l][0] = j0;      ri[l][1] = j1;      ri[l][2] = j2;
    }
    __syncthreads();   // rw/ri ready; pts/pf dead -> tile may alias

    // ---- Phase B: gather + blend + transpose ----
    for (int p = 0; p < 16; ++p) {
        int nl = p * 4 + w;
        float w0 = rw[nl][0], w1 = rw[nl][1], w2 = rw[nl][2];
        int i0g = ri[nl][0], i1g = ri[nl][1], i2g = ri[nl][2];
        const float4 va = ((const float4*)(x2 + ((size_t)b * N2_ + i0g) * C2_))[l];
        const float4 vb = ((const float4*)(x2 + ((size_t)b * N2_ + i1g) * C2_))[l];
        const float4 vc = ((const float4*)(x2 + ((size_t)b * N2_ + i2g) * C2_))[l];
        float fa[4] = {va.x, va.y, va.z, va.w};
        float fb[4] = {vb.x, vb.y, vb.z, vb.w};
        float fc[4] = {vc.x, vc.y, vc.z, vc.w};
        #pragma unroll
        for (int i = 0; i < 4; ++i) {
            float v = w0 * fa[i];
            v = fmaf(w1, fb[i], v);
            v = fmaf(w2, fc[i], v);
            sh.tile[l * 4 + i][nl] = f32_to_bf16_bits(v);
        }
    }
    __syncthreads();

    for (int r = 0; r < 64; ++r) {
        int c = r * 4 + w;
        interp_t[((size_t)b * C2_ + c) * K_ + n0 + l] = sh.tile[c][l];
    }
}

// ---------------------------------------------------------------------------
// Kernel 3: split-K GEMM, tile 128(o) x 64(c), BK=32, 16 iters.
// Grid 4(c) x 2(o) x 128 = 1024 blocks -> 4 blocks/CU.
// Epilogue: device-scope f32 atomicAdd into Z (pre-initialized with bias)
// — removes the 32 MB slab read + 4 MB rewrite of the reduce kernel.
// 8 adds per output element, uncontended; f32 reorder error ~ulp.
// ---------------------------------------------------------------------------
#define LDA 40
__global__ __launch_bounds__(256) void gemm_kernel(
    const unsigned short* __restrict__ W1b,
    const unsigned short* __restrict__ interp_t,
    float* __restrict__ Z)
{
    __shared__ unsigned short Alds[128][LDA];   // 10.24 KB
    __shared__ unsigned short Blds[64][LDA];    //  5.12 KB
    const int z  = blockIdx.z;
    const int b  = z >> 3;
    const int kc = z & 7;
    const int o0 = blockIdx.y * 128;
    const int c0 = blockIdx.x * 64;
    const int t = threadIdx.x;
    const int w = t >> 6, l = t & 63;
    const int arow = t >> 1, ahalf = t & 1;   // A staging: 2 threads/row
    const int brow = t >> 2, bq = t & 3;      // B staging: 4 threads/row
    const int ob = (w >> 1) * 64, cb = (w & 1) * 32;
    const int m = l & 15, kq = l >> 4;

    const unsigned short* Wp = W1b + (size_t)(o0 + arow) * K_ + kc * KCH_ + ahalf * 16;
    const unsigned short* Bp = interp_t + ((size_t)b * C2_ + (c0 + brow)) * K_ + kc * KCH_ + bq * 8;

    float4v acc[4][2] = {};

    for (int kk = 0; kk < KCH_; kk += 32) {
        uint4 av0 = *(const uint4*)(Wp + kk);
        uint4 av1 = *(const uint4*)(Wp + kk + 8);
        uint4 bv  = *(const uint4*)(Bp + kk);
        *(uint4*)&Alds[arow][ahalf * 16]     = av0;
        *(uint4*)&Alds[arow][ahalf * 16 + 8] = av1;
        *(uint4*)&Blds[brow][bq * 8]         = bv;
        __syncthreads();
        short8 bf0 = *(const short8*)&Blds[cb + m][kq * 8];
        short8 bf1 = *(const short8*)&Blds[cb + 16 + m][kq * 8];
        #pragma unroll
        for (int mi = 0; mi < 4; ++mi) {
            short8 af = *(const short8*)&Alds[ob + mi * 16 + m][kq * 8];
            acc[mi][0] = __builtin_amdgcn_mfma_f32_16x16x32_bf16(af, bf0, acc[mi][0], 0, 0, 0);
            acc[mi][1] = __builtin_amdgcn_mfma_f32_16x16x32_bf16(af, bf1, acc[mi][1], 0, 0, 0);
        }
        __syncthreads();
    }

    #pragma unroll
    for (int mi = 0; mi < 4; ++mi)
    #pragma unroll
    for (int ni = 0; ni < 2; ++ni)
    #pragma unroll
    for (int r = 0; r < 4; ++r) {
        int o = o0 + ob + mi * 16 + kq * 4 + r;
        int c = c0 + cb + ni * 16 + m;
        atomicAdd(&Z[((size_t)b * OUT_ + o) * C2_ + c], acc[mi][ni][r]);
    }
}

// ---------------------------------------------------------------------------
// Kernel 4: BN stats — read-only pass over final Z (4 MB), sum/sumsq per
// channel, one atomic pair per (block, channel).
// ---------------------------------------------------------------------------
__global__ __launch_bounds__(256) void stats_kernel(
    const float* __restrict__ Z, float* __restrict__ accum)
{
    const int b  = blockIdx.x >> 4;
    const int oq = blockIdx.x & 15;
    const int c  = threadIdx.x;
    float s = 0.0f, s2 = 0.0f;
    for (int o16 = 0; o16 < 16; ++o16) {
        int o = oq * 16 + o16;
        float v = Z[((size_t)b * OUT_ + o) * C2_ + c];
        s += v; s2 += v * v;
    }
    atomicAdd(&accum[c], s);
    atomicAdd(&accum[C2_ + c], s2);
}

// ---------------------------------------------------------------------------
// Kernel 5: normalize + affine + ReLU + f32 store (reads Z).
// ---------------------------------------------------------------------------
__global__ __launch_bounds__(256) void bn_kernel(
    const float* __restrict__ Z, const float* __restrict__ accum,
    const float* __restrict__ gamma, const float* __restrict__ beta,
    float* __restrict__ out)
{
    const int i = (blockIdx.x * 256 + threadIdx.x) * 4;
    float4 z = *(const float4*)(Z + i);
    float vals[4] = {z.x, z.y, z.z, z.w};
    const int cb = i & 255;
    float res[4];
    #pragma unroll
    for (int j = 0; j < 4; ++j) {
        int c = cb + j;
        float mean = accum[c] * (1.0f / 4096.0f);
        float var  = accum[C2_ + c] * (1.0f / 4096.0f) - mean * mean;
        float rstd = 1.0f / sqrtf(var + 1e-5f);
        float v = gamma[c] * ((vals[j] - mean) * rstd) + beta[c];
        res[j] = fmaxf(v, 0.0f);
    }
    *(float4*)(out + i) = make_float4(res[0], res[1], res[2], res[3]);
}

// ---------------------------------------------------------------------------
extern "C" void kernel_launch(void* const* d_in, const int* in_sizes, int n_in,
                              void* d_out, int out_size, void* d_ws, size_t ws_size,
                              hipStream_t stream) {
    const float* x2    = (const float*)d_in[1];
    const float* xyz1  = (const float*)d_in[2];
    const float* xyz2  = (const float*)d_in[3];
    const float* W1    = (const float*)d_in[4];
    const float* b1    = (const float*)d_in[5];
    const float* gamma = (const float*)d_in[6];
    const float* beta  = (const float*)d_in[7];

    char* ws = (char*)d_ws;
    unsigned short* interp_t = (unsigned short*)(ws);              // 33,554,432 B
    unsigned short* W1b      = (unsigned short*)(ws + 33554432);   //  2,097,152 B
    float*          Z        = (float*)(ws + 35651584);            //  4,194,304 B
    float*          accum    = (float*)(ws + 39845888);            //      2,048 B

    prep_kernel       <<<2048, 256, 0, stream>>>(W1, W1b, b1, Z, accum);
    knn_interp_kernel <<<dim3(64, 16), 256, 0, stream>>>(xyz1, xyz2, x2, interp_t);
    gemm_kernel       <<<dim3(4, 2, 128), 256, 0, stream>>>(W1b, interp_t, Z);
    stats_kernel      <<<256, 256, 0, stream>>>(Z, accum);
    bn_kernel         <<<1024, 256, 0, stream>>>(Z, accum, gamma, beta,
                                                 (float*)d_out);
}

// Round 13
// 162.891 us; speedup vs baseline: 1.0966x; 1.0966x over previous
//
#include <hip/hip_runtime.h>
#include <hip/hip_bf16.h>
#include <float.h>

#define B_    16
#define N1_   4096
#define N2_   1024
#define C2_   256
#define OUT_  256
#define K_    4096    // GEMM K == N1
#define SPLITK 8
#define KCH_  (K_ / SPLITK)     // 512
#define ZSLAB 1048576           // floats per partial slab (16*256*256)

typedef short short8 __attribute__((ext_vector_type(8)));
typedef float float4v __attribute__((ext_vector_type(4)));

static __device__ __forceinline__ unsigned short f32_to_bf16_bits(float v) {
    __hip_bfloat16 h = __float2bfloat16(v);
    return *(unsigned short*)&h;
}

// ---------------------------------------------------------------------------
// Kernel 0: convert W1 f32 -> bf16; block 0 also zeroes BN accumulators.
// ---------------------------------------------------------------------------
__global__ __launch_bounds__(256) void w1cvt_kernel(
    const float* __restrict__ W1, unsigned short* __restrict__ W1b,
    float* __restrict__ accum)
{
    if (blockIdx.x == 0) {
        accum[threadIdx.x] = 0.0f;
        accum[256 + threadIdx.x] = 0.0f;
    }
    const int i = (blockIdx.x * 256 + threadIdx.x) * 4;
    float4 v = *(const float4*)(W1 + i);
    ushort4 o;
    o.x = f32_to_bf16_bits(v.x);
    o.y = f32_to_bf16_bits(v.y);
    o.z = f32_to_bf16_bits(v.z);
    o.w = f32_to_bf16_bits(v.w);
    *(ushort4*)(W1b + i) = o;
}

// ---------------------------------------------------------------------------
// Fused knn + interp — proven R9/R11 structure (1 query/thread, 64 q/block,
// 1024 blocks = 4 blocks/CU). Key = distance dk = max(ss+2*(0.5|p|^2-dot),0)
// (non-negative -> float order == bit order), candidate index in low 10
// mantissa bits; smaller index wins ties (JAX stable top-k). Truncation
// 2^-13 relative to d -> flips only between near-equal neighbors (benign;
// absmax 0.035). Top-3 via 4-op min/med3/min(max) network; subtract folded
// into fma. Winners' distances recomputed exactly. Phase B: gather + blend +
// LDS-transpose, write bf16 interp_t[b][c][n] (K-major).
// ---------------------------------------------------------------------------
#define TPAD 65
struct KnnSh {
    float4 pts[N2_];          // (x, y, z, 0.5*|p|^2)   16 KB
    float  pf[4][64][3];      // per-wave packed top-3   3 KB
};
union ShUnion {
    KnnSh a;
    unsigned short tile[C2_][TPAD];   // transpose tile  33.3 KB
};

__global__ __launch_bounds__(256) void knn_interp_kernel(
    const float* __restrict__ xyz1,
    const float* __restrict__ xyz2,
    const float* __restrict__ x2,
    unsigned short* __restrict__ interp_t)
{
    __shared__ ShUnion sh;
    __shared__ float rw[64][3];
    __shared__ int   ri[64][3];

    const int b  = blockIdx.y;
    const int n0 = blockIdx.x * 64;
    const int t  = threadIdx.x;
    const int w  = t >> 6;
    const int l  = t & 63;

    // ---- stage candidates into LDS ----
    for (int r = 0; r < 4; ++r) {
        int j = r * 256 + t;
        const float* p = xyz2 + ((size_t)b * N2_ + j) * 3;
        float x = p[0], y = p[1], z = p[2];
        sh.a.pts[j] = make_float4(x, y, z, 0.5f * ((x * x + y * y) + z * z));
    }
    __syncthreads();

    const int n1 = n0 + l;
    const float* q = xyz1 + ((size_t)b * N1_ + n1) * 3;
    const float s0 = q[0], s1 = q[1], s2 = q[2];
    const float ns0 = -s0, ns1 = -s1, ns2 = -s2;
    const float ss = (s0 * s0 + s1 * s1) + s2 * s2;

    // ---- Phase A: scan (wave w covers blocked quarter [256w, 256w+256)) ----
    const int jbase = w << 8;
    float f0 = FLT_MAX, f1 = FLT_MAX, f2 = FLT_MAX;

    #pragma unroll 4
    for (int jj = 0; jj < 256; ++jj) {
        const int j = jbase + jj;
        float4 pq = sh.a.pts[j];
        float acc = fmaf(ns0, pq.x, pq.w);
        acc = fmaf(ns1, pq.y, acc);
        acc = fmaf(ns2, pq.z, acc);
        float dk = fmaxf(fmaf(2.0f, acc, ss), 0.0f);
        float fp = __int_as_float((__float_as_int(dk) & 0xFFFFFC00) | j);
        float nf0 = fminf(fp, f0);
        float nf1 = __builtin_amdgcn_fmed3f(fp, f0, f1);
        float nf2 = fminf(f2, fmaxf(fp, f1));
        f0 = nf0; f1 = nf1; f2 = nf2;
    }

    sh.a.pf[w][l][0] = f0; sh.a.pf[w][l][1] = f1; sh.a.pf[w][l][2] = f2;
    __syncthreads();

    if (w == 0) {
        float g0 = FLT_MAX, g1 = FLT_MAX, g2 = FLT_MAX;
        #pragma unroll
        for (int p = 0; p < 4; ++p)
        #pragma unroll
        for (int r = 0; r < 3; ++r) {
            float fp = sh.a.pf[p][l][r];
            float n0v = fminf(fp, g0);
            float n1v = __builtin_amdgcn_fmed3f(fp, g0, g1);
            float n2v = fminf(g2, fmaxf(fp, g1));
            g0 = n0v; g1 = n1v; g2 = n2v;
        }
        int j0 = __float_as_int(g0) & 1023;
        int j1 = __float_as_int(g1) & 1023;
        int j2 = __float_as_int(g2) & 1023;
        const float4 p0 = sh.a.pts[j0];
        const float4 p1 = sh.a.pts[j1];
        const float4 p2 = sh.a.pts[j2];
        float d0 = ss + 2.0f * (p0.w - ((s0 * p0.x + s1 * p0.y) + s2 * p0.z));
        float d1 = ss + 2.0f * (p1.w - ((s0 * p1.x + s1 * p1.y) + s2 * p1.z));
        float d2 = ss + 2.0f * (p2.w - ((s0 * p2.x + s1 * p2.y) + s2 * p2.z));
        float r0 = 1.0f / (d0 + 1e-8f);
        float r1 = 1.0f / (d1 + 1e-8f);
        float r2 = 1.0f / (d2 + 1e-8f);
        float s  = (r0 + r1) + r2;
        rw[l][0] = r0 / s;  rw[l][1] = r1 / s;  rw[l][2] = r2 / s;
        ri[l][0] = j0;      ri[l][1] = j1;      ri[l][2] = j2;
    }
    __syncthreads();   // rw/ri ready; pts/pf dead -> tile may alias

    // ---- Phase B: gather + blend + transpose ----
    for (int p = 0; p < 16; ++p) {
        int nl = p * 4 + w;
        float w0 = rw[nl][0], w1 = rw[nl][1], w2 = rw[nl][2];
        int i0g = ri[nl][0], i1g = ri[nl][1], i2g = ri[nl][2];
        const float4 va = ((const float4*)(x2 + ((size_t)b * N2_ + i0g) * C2_))[l];
        const float4 vb = ((const float4*)(x2 + ((size_t)b * N2_ + i1g) * C2_))[l];
        const float4 vc = ((const float4*)(x2 + ((size_t)b * N2_ + i2g) * C2_))[l];
        float fa[4] = {va.x, va.y, va.z, va.w};
        float fb[4] = {vb.x, vb.y, vb.z, vb.w};
        float fc[4] = {vc.x, vc.y, vc.z, vc.w};
        #pragma unroll
        for (int i = 0; i < 4; ++i) {
            float v = w0 * fa[i];
            v = fmaf(w1, fb[i], v);
            v = fmaf(w2, fc[i], v);
            sh.tile[l * 4 + i][nl] = f32_to_bf16_bits(v);
        }
    }
    __syncthreads();

    for (int r = 0; r < 64; ++r) {
        int c = r * 4 + w;
        interp_t[((size_t)b * C2_ + c) * K_ + n0 + l] = sh.tile[c][l];
    }
}

// ---------------------------------------------------------------------------
// Kernel 3: split-K GEMM, tile 128(o) x 64(c), BK=32, 16 iters, with
// REGISTER-PREFETCHED staging: iteration k+1's three 16-B global loads are
// issued right after the first barrier and consumed (ds_write) only at the
// next iteration — the MFMA+ds_read section hides the L2/L3 latency that
// R11/R12 paid inside the barrier pair. Epilogue: plain slab stores
// (R12's atomic epilogue cost ~15 µs — reverted).
// Grid 4(c) x 2(o) x 128 = 1024 blocks -> 4 blocks/CU.
// ---------------------------------------------------------------------------
#define LDA 40
__global__ __launch_bounds__(256) void gemm_kernel(
    const unsigned short* __restrict__ W1b,
    const unsigned short* __restrict__ interp_t,
    float* __restrict__ Zp)
{
    __shared__ unsigned short Alds[128][LDA];   // 10.24 KB
    __shared__ unsigned short Blds[64][LDA];    //  5.12 KB
    const int z  = blockIdx.z;
    const int b  = z >> 3;
    const int kc = z & 7;
    const int o0 = blockIdx.y * 128;
    const int c0 = blockIdx.x * 64;
    const int t = threadIdx.x;
    const int w = t >> 6, l = t & 63;
    const int arow = t >> 1, ahalf = t & 1;   // A staging: 2 threads/row
    const int brow = t >> 2, bq = t & 3;      // B staging: 4 threads/row
    const int ob = (w >> 1) * 64, cb = (w & 1) * 32;
    const int m = l & 15, kq = l >> 4;

    const unsigned short* Wp = W1b + (size_t)(o0 + arow) * K_ + kc * KCH_ + ahalf * 16;
    const unsigned short* Bp = interp_t + ((size_t)b * C2_ + (c0 + brow)) * K_ + kc * KCH_ + bq * 8;

    float4v acc[4][2] = {};

    // prime the register pipeline with iteration 0's staging data
    uint4 av0 = *(const uint4*)(Wp);
    uint4 av1 = *(const uint4*)(Wp + 8);
    uint4 bv  = *(const uint4*)(Bp);

    for (int kk = 0; kk < KCH_; kk += 32) {
        *(uint4*)&Alds[arow][ahalf * 16]     = av0;
        *(uint4*)&Alds[arow][ahalf * 16 + 8] = av1;
        *(uint4*)&Blds[brow][bq * 8]         = bv;
        __syncthreads();

        // prefetch next iteration while this one computes
        if (kk + 32 < KCH_) {
            av0 = *(const uint4*)(Wp + kk + 32);
            av1 = *(const uint4*)(Wp + kk + 40);
            bv  = *(const uint4*)(Bp + kk + 32);
        }

        short8 bf0 = *(const short8*)&Blds[cb + m][kq * 8];
        short8 bf1 = *(const short8*)&Blds[cb + 16 + m][kq * 8];
        #pragma unroll
        for (int mi = 0; mi < 4; ++mi) {
            short8 af = *(const short8*)&Alds[ob + mi * 16 + m][kq * 8];
            acc[mi][0] = __builtin_amdgcn_mfma_f32_16x16x32_bf16(af, bf0, acc[mi][0], 0, 0, 0);
            acc[mi][1] = __builtin_amdgcn_mfma_f32_16x16x32_bf16(af, bf1, acc[mi][1], 0, 0, 0);
        }
        __syncthreads();
    }

    float* Zslab = Zp + (size_t)kc * ZSLAB;
    #pragma unroll
    for (int mi = 0; mi < 4; ++mi)
    #pragma unroll
    for (int ni = 0; ni < 2; ++ni)
    #pragma unroll
    for (int r = 0; r < 4; ++r) {
        int o = o0 + ob + mi * 16 + kq * 4 + r;
        int c = c0 + cb + ni * 16 + m;
        Zslab[((size_t)b * OUT_ + o) * C2_ + c] = acc[mi][ni][r];
    }
}

// ---------------------------------------------------------------------------
// Kernel 4: reduce 8 partial slabs + bias -> final Z (slab 0), and
// accumulate BN stats (sum, sumsq per channel) via one atomic pair per block.
// ---------------------------------------------------------------------------
__global__ __launch_bounds__(256) void reduce_stats_kernel(
    float* __restrict__ Zp, const float* __restrict__ b1,
    float* __restrict__ accum)
{
    const int b  = blockIdx.x >> 4;
    const int oq = blockIdx.x & 15;
    const int c  = threadIdx.x;
    float s = 0.0f, s2 = 0.0f;
    for (int o16 = 0; o16 < 16; ++o16) {
        int o = oq * 16 + o16;
        size_t base = ((size_t)b * OUT_ + o) * C2_ + c;
        float v = b1[o];
        #pragma unroll
        for (int sl = 0; sl < SPLITK; ++sl)
            v += Zp[base + (size_t)sl * ZSLAB];
        Zp[base] = v;
        s += v; s2 += v * v;
    }
    atomicAdd(&accum[c], s);
    atomicAdd(&accum[C2_ + c], s2);
}

// ---------------------------------------------------------------------------
// Kernel 5: normalize + affine + ReLU + f32 store (reads final Z = slab 0).
// ---------------------------------------------------------------------------
__global__ __launch_bounds__(256) void bn_kernel(
    const float* __restrict__ Z, const float* __restrict__ accum,
    const float* __restrict__ gamma, const float* __restrict__ beta,
    float* __restrict__ out)
{
    const int i = (blockIdx.x * 256 + threadIdx.x) * 4;
    float4 z = *(const float4*)(Z + i);
    float vals[4] = {z.x, z.y, z.z, z.w};
    const int cb = i & 255;
    float res[4];
    #pragma unroll
    for (int j = 0; j < 4; ++j) {
        int c = cb + j;
        float mean = accum[c] * (1.0f / 4096.0f);
        float var  = accum[C2_ + c] * (1.0f / 4096.0f) - mean * mean;
        float rstd = 1.0f / sqrtf(var + 1e-5f);
        float v = gamma[c] * ((vals[j] - mean) * rstd) + beta[c];
        res[j] = fmaxf(v, 0.0f);
    }
    *(float4*)(out + i) = make_float4(res[0], res[1], res[2], res[3]);
}

// ---------------------------------------------------------------------------
extern "C" void kernel_launch(void* const* d_in, const int* in_sizes, int n_in,
                              void* d_out, int out_size, void* d_ws, size_t ws_size,
                              hipStream_t stream) {
    const float* x2    = (const float*)d_in[1];
    const float* xyz1  = (const float*)d_in[2];
    const float* xyz2  = (const float*)d_in[3];
    const float* W1    = (const float*)d_in[4];
    const float* b1    = (const float*)d_in[5];
    const float* gamma = (const float*)d_in[6];
    const float* beta  = (const float*)d_in[7];

    char* ws = (char*)d_ws;
    unsigned short* interp_t = (unsigned short*)(ws);              // 33,554,432 B
    unsigned short* W1b      = (unsigned short*)(ws + 33554432);   //  2,097,152 B
    float*          Zp       = (float*)(ws + 35651584);            // 33,554,432 B (8 slabs)
    float*          accum    = (float*)(ws + 69206016);            //      2,048 B

    w1cvt_kernel      <<<1024, 256, 0, stream>>>(W1, W1b, accum);
    knn_interp_kernel <<<dim3(64, 16), 256, 0, stream>>>(xyz1, xyz2, x2, interp_t);
    gemm_kernel       <<<dim3(4, 2, 128), 256, 0, stream>>>(W1b, interp_t, Zp);
    reduce_stats_kernel<<<256, 256, 0, stream>>>(Zp, b1, accum);
    bn_kernel         <<<1024, 256, 0, stream>>>(Zp, accum, gamma, beta,
                                                 (float*)d_out);
}

// Round 14
// 159.232 us; speedup vs baseline: 1.1217x; 1.0230x over previous
//
#include <hip/hip_runtime.h>
#include <hip/hip_bf16.h>
#include <float.h>

#define B_    16
#define N1_   4096
#define N2_   1024
#define C2_   256
#define OUT_  256
#define K_    4096    // GEMM K == N1
#define SPLITK 8
#define KCH_  (K_ / SPLITK)     // 512
#define ZSLAB 1048576           // floats per partial slab (16*256*256)

typedef short short8 __attribute__((ext_vector_type(8)));
typedef float float4v __attribute__((ext_vector_type(4)));

static __device__ __forceinline__ unsigned short f32_to_bf16_bits(float v) {
    __hip_bfloat16 h = __float2bfloat16(v);
    return *(unsigned short*)&h;
}

// ---------------------------------------------------------------------------
// Fused (w1cvt + knn + interp) in ONE dispatch, block-role branch:
// blocks [0,1024): convert W1 f32->bf16 (block 0 also zeroes BN accum) —
//   fast, retire early, free their CU slots for the knn blocks behind them.
// blocks [1024,2048): the proven R9/R11 knn+interp (1 query/thread,
//   64 q/block). Key = distance dk = max(ss+2*(0.5|p|^2-dot),0)
//   (non-negative -> float order == bit order), candidate index in low 10
//   mantissa bits; smaller index wins ties (JAX stable top-k). Truncation
//   2^-13 relative to d -> flips only between near-equal neighbors (benign;
//   absmax 0.035). Top-3 via 4-op min/med3/min(max) network. Winners'
//   distances recomputed exactly. Phase B: gather + blend + LDS-transpose,
//   write bf16 interp_t[b][c][n] (K-major).
// ---------------------------------------------------------------------------
#define TPAD 65
struct KnnSh {
    float4 pts[N2_];          // (x, y, z, 0.5*|p|^2)   16 KB
    float  pf[4][64][3];      // per-wave packed top-3   3 KB
};
union ShUnion {
    KnnSh a;
    unsigned short tile[C2_][TPAD];   // transpose tile  33.3 KB
};

__global__ __launch_bounds__(256) void knn_interp_kernel(
    const float* __restrict__ xyz1,
    const float* __restrict__ xyz2,
    const float* __restrict__ x2,
    unsigned short* __restrict__ interp_t,
    const float* __restrict__ W1,
    unsigned short* __restrict__ W1b,
    float* __restrict__ accum)
{
    __shared__ ShUnion sh;
    __shared__ float rw[64][3];
    __shared__ int   ri[64][3];

    const int bid = blockIdx.x;
    const int t   = threadIdx.x;

    if (bid < 1024) {   // ---- role: W1 convert (+ accum zero) ----
        if (bid == 0) {
            accum[t] = 0.0f;
            accum[256 + t] = 0.0f;
        }
        const int i = (bid * 256 + t) * 4;
        float4 v = *(const float4*)(W1 + i);
        ushort4 o;
        o.x = f32_to_bf16_bits(v.x);
        o.y = f32_to_bf16_bits(v.y);
        o.z = f32_to_bf16_bits(v.z);
        o.w = f32_to_bf16_bits(v.w);
        *(ushort4*)(W1b + i) = o;
        return;
    }

    // ---- role: knn + interp ----
    const int rem = bid - 1024;
    const int b   = rem >> 6;
    const int n0  = (rem & 63) * 64;
    const int w   = t >> 6;
    const int l   = t & 63;

    for (int r = 0; r < 4; ++r) {
        int j = r * 256 + t;
        const float* p = xyz2 + ((size_t)b * N2_ + j) * 3;
        float x = p[0], y = p[1], z = p[2];
        sh.a.pts[j] = make_float4(x, y, z, 0.5f * ((x * x + y * y) + z * z));
    }
    __syncthreads();

    const int n1 = n0 + l;
    const float* q = xyz1 + ((size_t)b * N1_ + n1) * 3;
    const float s0 = q[0], s1 = q[1], s2 = q[2];
    const float ns0 = -s0, ns1 = -s1, ns2 = -s2;
    const float ss = (s0 * s0 + s1 * s1) + s2 * s2;

    const int jbase = w << 8;
    float f0 = FLT_MAX, f1 = FLT_MAX, f2 = FLT_MAX;

    #pragma unroll 4
    for (int jj = 0; jj < 256; ++jj) {
        const int j = jbase + jj;
        float4 pq = sh.a.pts[j];
        float acc = fmaf(ns0, pq.x, pq.w);
        acc = fmaf(ns1, pq.y, acc);
        acc = fmaf(ns2, pq.z, acc);
        float dk = fmaxf(fmaf(2.0f, acc, ss), 0.0f);
        float fp = __int_as_float((__float_as_int(dk) & 0xFFFFFC00) | j);
        float nf0 = fminf(fp, f0);
        float nf1 = __builtin_amdgcn_fmed3f(fp, f0, f1);
        float nf2 = fminf(f2, fmaxf(fp, f1));
        f0 = nf0; f1 = nf1; f2 = nf2;
    }

    sh.a.pf[w][l][0] = f0; sh.a.pf[w][l][1] = f1; sh.a.pf[w][l][2] = f2;
    __syncthreads();

    if (w == 0) {
        float g0 = FLT_MAX, g1 = FLT_MAX, g2 = FLT_MAX;
        #pragma unroll
        for (int p = 0; p < 4; ++p)
        #pragma unroll
        for (int r = 0; r < 3; ++r) {
            float fp = sh.a.pf[p][l][r];
            float n0v = fminf(fp, g0);
            float n1v = __builtin_amdgcn_fmed3f(fp, g0, g1);
            float n2v = fminf(g2, fmaxf(fp, g1));
            g0 = n0v; g1 = n1v; g2 = n2v;
        }
        int j0 = __float_as_int(g0) & 1023;
        int j1 = __float_as_int(g1) & 1023;
        int j2 = __float_as_int(g2) & 1023;
        const float4 p0 = sh.a.pts[j0];
        const float4 p1 = sh.a.pts[j1];
        const float4 p2 = sh.a.pts[j2];
        float d0 = ss + 2.0f * (p0.w - ((s0 * p0.x + s1 * p0.y) + s2 * p0.z));
        float d1 = ss + 2.0f * (p1.w - ((s0 * p1.x + s1 * p1.y) + s2 * p1.z));
        float d2 = ss + 2.0f * (p2.w - ((s0 * p2.x + s1 * p2.y) + s2 * p2.z));
        float r0 = 1.0f / (d0 + 1e-8f);
        float r1 = 1.0f / (d1 + 1e-8f);
        float r2 = 1.0f / (d2 + 1e-8f);
        float s  = (r0 + r1) + r2;
        rw[l][0] = r0 / s;  rw[l][1] = r1 / s;  rw[l][2] = r2 / s;
        ri[l][0] = j0;      ri[l][1] = j1;      ri[l][2] = j2;
    }
    __syncthreads();   // rw/ri ready; pts/pf dead -> tile may alias

    for (int p = 0; p < 16; ++p) {
        int nl = p * 4 + w;
        float w0 = rw[nl][0], w1 = rw[nl][1], w2 = rw[nl][2];
        int i0g = ri[nl][0], i1g = ri[nl][1], i2g = ri[nl][2];
        const float4 va = ((const float4*)(x2 + ((size_t)b * N2_ + i0g) * C2_))[l];
        const float4 vb = ((const float4*)(x2 + ((size_t)b * N2_ + i1g) * C2_))[l];
        const float4 vc = ((const float4*)(x2 + ((size_t)b * N2_ + i2g) * C2_))[l];
        float fa[4] = {va.x, va.y, va.z, va.w};
        float fb[4] = {vb.x, vb.y, vb.z, vb.w};
        float fc[4] = {vc.x, vc.y, vc.z, vc.w};
        #pragma unroll
        for (int i = 0; i < 4; ++i) {
            float v = w0 * fa[i];
            v = fmaf(w1, fb[i], v);
            v = fmaf(w2, fc[i], v);
            sh.tile[l * 4 + i][nl] = f32_to_bf16_bits(v);
        }
    }
    __syncthreads();

    for (int r = 0; r < 64; ++r) {
        int c = r * 4 + w;
        interp_t[((size_t)b * C2_ + c) * K_ + n0 + l] = sh.tile[c][l];
    }
}

// ---------------------------------------------------------------------------
// Kernel 3: split-K GEMM, tile 128(o) x 64(c), BK=64 -> 8 iterations
// (R13 showed the stall is barrier count, not load latency: halve barriers,
// same LDS instr count per K-element). Register prefetch retained.
// Grid 4(c) x 2(o) x 128 = 1024 blocks -> 4 blocks/CU (LDS 27.6 KB).
// ---------------------------------------------------------------------------
#define LDA 72
__global__ __launch_bounds__(256) void gemm_kernel(
    const unsigned short* __restrict__ W1b,
    const unsigned short* __restrict__ interp_t,
    float* __restrict__ Zp)
{
    __shared__ unsigned short Alds[128][LDA];   // 18.4 KB
    __shared__ unsigned short Blds[64][LDA];    //  9.2 KB
    const int z  = blockIdx.z;
    const int b  = z >> 3;
    const int kc = z & 7;
    const int o0 = blockIdx.y * 128;
    const int c0 = blockIdx.x * 64;
    const int t = threadIdx.x;
    const int w = t >> 6, l = t & 63;
    const int arow = t >> 1, ahalf = t & 1;   // A staging: 2 thr/row, 32 elems each
    const int brow = t >> 2, bq = t & 3;      // B staging: 4 thr/row, 16 elems each
    const int ob = (w >> 1) * 64, cb = (w & 1) * 32;
    const int m = l & 15, kq = l >> 4;

    const unsigned short* Wp = W1b + (size_t)(o0 + arow) * K_ + kc * KCH_ + ahalf * 32;
    const unsigned short* Bp = interp_t + ((size_t)b * C2_ + (c0 + brow)) * K_ + kc * KCH_ + bq * 16;

    float4v acc[4][2] = {};

    uint4 a0 = *(const uint4*)(Wp);
    uint4 a1 = *(const uint4*)(Wp + 8);
    uint4 a2 = *(const uint4*)(Wp + 16);
    uint4 a3 = *(const uint4*)(Wp + 24);
    uint4 b0 = *(const uint4*)(Bp);
    uint4 b1 = *(const uint4*)(Bp + 8);

    for (int kk = 0; kk < KCH_; kk += 64) {
        *(uint4*)&Alds[arow][ahalf * 32]      = a0;
        *(uint4*)&Alds[arow][ahalf * 32 + 8]  = a1;
        *(uint4*)&Alds[arow][ahalf * 32 + 16] = a2;
        *(uint4*)&Alds[arow][ahalf * 32 + 24] = a3;
        *(uint4*)&Blds[brow][bq * 16]         = b0;
        *(uint4*)&Blds[brow][bq * 16 + 8]     = b1;
        __syncthreads();

        if (kk + 64 < KCH_) {
            a0 = *(const uint4*)(Wp + kk + 64);
            a1 = *(const uint4*)(Wp + kk + 72);
            a2 = *(const uint4*)(Wp + kk + 80);
            a3 = *(const uint4*)(Wp + kk + 88);
            b0 = *(const uint4*)(Bp + kk + 64);
            b1 = *(const uint4*)(Bp + kk + 72);
        }

        #pragma unroll
        for (int ks = 0; ks < 64; ks += 32) {
            short8 bf0 = *(const short8*)&Blds[cb + m][ks + kq * 8];
            short8 bf1 = *(const short8*)&Blds[cb + 16 + m][ks + kq * 8];
            #pragma unroll
            for (int mi = 0; mi < 4; ++mi) {
                short8 af = *(const short8*)&Alds[ob + mi * 16 + m][ks + kq * 8];
                acc[mi][0] = __builtin_amdgcn_mfma_f32_16x16x32_bf16(af, bf0, acc[mi][0], 0, 0, 0);
                acc[mi][1] = __builtin_amdgcn_mfma_f32_16x16x32_bf16(af, bf1, acc[mi][1], 0, 0, 0);
            }
        }
        __syncthreads();
    }

    float* Zslab = Zp + (size_t)kc * ZSLAB;
    #pragma unroll
    for (int mi = 0; mi < 4; ++mi)
    #pragma unroll
    for (int ni = 0; ni < 2; ++ni)
    #pragma unroll
    for (int r = 0; r < 4; ++r) {
        int o = o0 + ob + mi * 16 + kq * 4 + r;
        int c = c0 + cb + ni * 16 + m;
        Zslab[((size_t)b * OUT_ + o) * C2_ + c] = acc[mi][ni][r];
    }
}

// ---------------------------------------------------------------------------
// Kernel 4: reduce 8 partial slabs + bias -> final Z (slab 0), and
// accumulate BN stats (sum, sumsq per channel) via one atomic pair per block.
// ---------------------------------------------------------------------------
__global__ __launch_bounds__(256) void reduce_stats_kernel(
    float* __restrict__ Zp, const float* __restrict__ b1,
    float* __restrict__ accum)
{
    const int b  = blockIdx.x >> 4;
    const int oq = blockIdx.x & 15;
    const int c  = threadIdx.x;
    float s = 0.0f, s2 = 0.0f;
    for (int o16 = 0; o16 < 16; ++o16) {
        int o = oq * 16 + o16;
        size_t base = ((size_t)b * OUT_ + o) * C2_ + c;
        float v = b1[o];
        #pragma unroll
        for (int sl = 0; sl < SPLITK; ++sl)
            v += Zp[base + (size_t)sl * ZSLAB];
        Zp[base] = v;
        s += v; s2 += v * v;
    }
    atomicAdd(&accum[c], s);
    atomicAdd(&accum[C2_ + c], s2);
}

// ---------------------------------------------------------------------------
// Kernel 5: normalize + affine + ReLU + f32 store (reads final Z = slab 0).
// ---------------------------------------------------------------------------
__global__ __launch_bounds__(256) void bn_kernel(
    const float* __restrict__ Z, const float* __restrict__ accum,
    const float* __restrict__ gamma, const float* __restrict__ beta,
    float* __restrict__ out)
{
    const int i = (blockIdx.x * 256 + threadIdx.x) * 4;
    float4 z = *(const float4*)(Z + i);
    float vals[4] = {z.x, z.y, z.z, z.w};
    const int cb = i & 255;
    float res[4];
    #pragma unroll
    for (int j = 0; j < 4; ++j) {
        int c = cb + j;
        float mean = accum[c] * (1.0f / 4096.0f);
        float var  = accum[C2_ + c] * (1.0f / 4096.0f) - mean * mean;
        float rstd = 1.0f / sqrtf(var + 1e-5f);
        float v = gamma[c] * ((vals[j] - mean) * rstd) + beta[c];
        res[j] = fmaxf(v, 0.0f);
    }
    *(float4*)(out + i) = make_float4(res[0], res[1], res[2], res[3]);
}

// ---------------------------------------------------------------------------
extern "C" void kernel_launch(void* const* d_in, const int* in_sizes, int n_in,
                              void* d_out, int out_size, void* d_ws, size_t ws_size,
                              hipStream_t stream) {
    const float* x2    = (const float*)d_in[1];
    const float* xyz1  = (const float*)d_in[2];
    const float* xyz2  = (const float*)d_in[3];
    const float* W1    = (const float*)d_in[4];
    const float* b1    = (const float*)d_in[5];
    const float* gamma = (const float*)d_in[6];
    const float* beta  = (const float*)d_in[7];

    char* ws = (char*)d_ws;
    unsigned short* interp_t = (unsigned short*)(ws);              // 33,554,432 B
    unsigned short* W1b      = (unsigned short*)(ws + 33554432);   //  2,097,152 B
    float*          Zp       = (float*)(ws + 35651584);            // 33,554,432 B (8 slabs)
    float*          accum    = (float*)(ws + 69206016);            //      2,048 B

    knn_interp_kernel <<<2048, 256, 0, stream>>>(xyz1, xyz2, x2, interp_t,
                                                 W1, W1b, accum);
    gemm_kernel       <<<dim3(4, 2, 128), 256, 0, stream>>>(W1b, interp_t, Zp);
    reduce_stats_kernel<<<256, 256, 0, stream>>>(Zp, b1, accum);
    bn_kernel         <<<1024, 256, 0, stream>>>(Zp, accum, gamma, beta,
                                                 (float*)d_out);
}